// Round 1
// baseline (489.564 us; speedup 1.0000x reference)
//
#include <hip/hip_runtime.h>
#include <hip/hip_bf16.h>

// Problem constants
#define BATCH 4096
#define IN_SZ 512
#define HID_SZ 2048
#define OUT_SZ 512
#define NLAYER 4
#define INNER 2560  // 512 + 2048

typedef __attribute__((ext_vector_type(8))) short bf16x8;
typedef __attribute__((ext_vector_type(4))) float f32x4;

__device__ __forceinline__ unsigned short f2bf(float f) {
  unsigned int u = __float_as_uint(f);
  u += 0x7fff + ((u >> 16) & 1);   // RNE
  return (unsigned short)(u >> 16);
}

__device__ __forceinline__ void gload16(const void* g, void* l) {
  __builtin_amdgcn_global_load_lds(
      (const __attribute__((address_space(1))) unsigned int*)g,
      (__attribute__((address_space(3))) unsigned int*)l,
      16, 0, 0);
}

// ---------------- conversion kernels ----------------

__global__ void cvt_f32_bf16(const float* __restrict__ in,
                             unsigned short* __restrict__ out, int n4) {
  int i = blockIdx.x * blockDim.x + threadIdx.x;
  const int stride = gridDim.x * blockDim.x;
  for (; i < n4; i += stride) {
    float4 v = *reinterpret_cast<const float4*>(in + (long)i * 4);
    ushort4 o;
    o.x = f2bf(v.x); o.y = f2bf(v.y); o.z = f2bf(v.z); o.w = f2bf(v.w);
    *reinterpret_cast<ushort4*>(out + (long)i * 4) = o;
  }
}

// combined = concat(x[4096,512], h[4096,2048]) -> bf16 [4096,2560]
__global__ void build_combined(const float* __restrict__ x,
                               const float* __restrict__ h,
                               unsigned short* __restrict__ out) {
  const int n4 = BATCH * INNER / 4;   // 2,621,440
  int i = blockIdx.x * blockDim.x + threadIdx.x;
  const int stride = gridDim.x * blockDim.x;
  for (; i < n4; i += stride) {
    int row = i / (INNER / 4);
    int c4 = i - row * (INNER / 4);
    const float* src = (c4 < IN_SZ / 4) ? (x + (long)row * IN_SZ + c4 * 4)
                                        : (h + (long)row * HID_SZ + (c4 - IN_SZ / 4) * 4);
    float4 v = *reinterpret_cast<const float4*>(src);
    ushort4 o;
    o.x = f2bf(v.x); o.y = f2bf(v.y); o.z = f2bf(v.z); o.w = f2bf(v.w);
    *reinterpret_cast<ushort4*>(out + (long)i * 4) = o;
  }
}

// ---------------- GEMM: C = act(A * B^T + bias) ----------------
// A: [4096][K] bf16 row-major, B: [N][K] bf16 row-major (einsum 'bi,oi->bo')
// ACT: 0 = relu -> bf16 C, 1 = tanh -> f32 C, 2 = none -> f32 C
// tile 128x128, BK=32, 4 waves (2x2), each wave 64x64 = 4x4 fragments 16x16

template <int ACT>
__global__ __launch_bounds__(256)
void gemm_bt(const unsigned short* __restrict__ A,
             const unsigned short* __restrict__ B,
             const float* __restrict__ bias,
             void* __restrict__ C, int N, int K) {
  __shared__ unsigned short As[128 * 32];  // 8 KB
  __shared__ unsigned short Bs[128 * 32];  // 8 KB

  const int tid  = threadIdx.x;
  const int wave = tid >> 6;
  const int lane = tid & 63;
  const int row0 = blockIdx.x * 128;
  const int col0 = blockIdx.y * 128;
  const int wr = wave >> 1, wc = wave & 1;

  f32x4 acc[4][4] = {};

  // staging: segment s = instr*4 + wave covers 16 rows; lane l -> row s*16+l/4, k (l&3)*8
  const int kcol = (lane & 3) * 8;
  const unsigned short* Ag0 = A + (long)(row0 + wave * 16 + (lane >> 2)) * K + kcol;
  const unsigned short* Ag1 = Ag0 + 64 * (long)K;
  const unsigned short* Bg0 = B + (long)(col0 + wave * 16 + (lane >> 2)) * K + kcol;
  const unsigned short* Bg1 = Bg0 + 64 * (long)K;
  unsigned short* AsW0 = As + wave * 512;         // instr0 segment base (wave-uniform)
  unsigned short* AsW1 = As + 2048 + wave * 512;  // instr1
  unsigned short* BsW0 = Bs + wave * 512;
  unsigned short* BsW1 = Bs + 2048 + wave * 512;

  const int fr = lane & 15;
  const int fk = (lane >> 4) * 8;
  const unsigned short* Abase = As + (wr * 64 + fr) * 32 + fk;
  const unsigned short* Bbase = Bs + (wc * 64 + fr) * 32 + fk;

  for (int k0 = 0; k0 < K; k0 += 32) {
    gload16(Ag0 + k0, AsW0);
    gload16(Ag1 + k0, AsW1);
    gload16(Bg0 + k0, BsW0);
    gload16(Bg1 + k0, BsW1);
    __syncthreads();

    bf16x8 a[4], b[4];
#pragma unroll
    for (int m = 0; m < 4; ++m)
      a[m] = *reinterpret_cast<const bf16x8*>(Abase + m * 16 * 32);
#pragma unroll
    for (int n = 0; n < 4; ++n)
      b[n] = *reinterpret_cast<const bf16x8*>(Bbase + n * 16 * 32);
#pragma unroll
    for (int m = 0; m < 4; ++m)
#pragma unroll
      for (int n = 0; n < 4; ++n)
        acc[m][n] = __builtin_amdgcn_mfma_f32_16x16x32_bf16(a[m], b[n], acc[m][n], 0, 0, 0);
    __syncthreads();
  }

  // epilogue: C/D layout col = lane&15, row = (lane>>4)*4 + j
  const int r0 = (lane >> 4) * 4;
#pragma unroll
  for (int n = 0; n < 4; ++n) {
    const int col = col0 + wc * 64 + n * 16 + fr;
    const float bv = bias[col];
#pragma unroll
    for (int m = 0; m < 4; ++m) {
      const int row = row0 + wr * 64 + m * 16 + r0;
#pragma unroll
      for (int j = 0; j < 4; ++j) {
        float v = acc[m][n][j] + bv;
        if (ACT == 0) {
          v = fmaxf(v, 0.0f);
          reinterpret_cast<unsigned short*>(C)[(long)(row + j) * N + col] = f2bf(v);
        } else if (ACT == 1) {
          reinterpret_cast<float*>(C)[(long)(row + j) * N + col] = tanhf(v);
        } else {
          reinterpret_cast<float*>(C)[(long)(row + j) * N + col] = v;
        }
      }
    }
  }
}

// ---------------- launcher ----------------

extern "C" void kernel_launch(void* const* d_in, const int* in_sizes, int n_in,
                              void* d_out, int out_size, void* d_ws, size_t ws_size,
                              hipStream_t stream) {
  const float* x   = (const float*)d_in[0];  // [4096,512]
  const float* h   = (const float*)d_in[1];  // [4096,2048]
  const float* Wl  = (const float*)d_in[2];  // [4,2560,2560]
  const float* bl  = (const float*)d_in[3];  // [4,2560]
  const float* Wih = (const float*)d_in[4];  // [2048,2560]
  const float* bih = (const float*)d_in[5];  // [2048]
  const float* Wio = (const float*)d_in[6];  // [512,2560]
  const float* bio = (const float*)d_in[7];  // [512]

  // ws layout (bf16/ushort elements)
  unsigned short* ws   = (unsigned short*)d_ws;
  unsigned short* Wlb  = ws;                                  // 4*2560*2560 = 26,214,400
  unsigned short* Wihb = Wlb + (long)NLAYER * INNER * INNER;  // 2048*2560  =  5,242,880
  unsigned short* Wiob = Wihb + (long)HID_SZ * INNER;         // 512*2560   =  1,310,720
  unsigned short* act0 = Wiob + (long)OUT_SZ * INNER;         // 4096*2560
  unsigned short* act1 = act0 + (long)BATCH * INNER;
  // total ~107.5 MB of ws

  float* out_output = (float*)d_out;                       // [4096,512]
  float* out_hidden = (float*)d_out + (long)BATCH * OUT_SZ;  // [4096,2048]

  // 1. convert weights fp32 -> bf16
  cvt_f32_bf16<<<2048, 256, 0, stream>>>(Wl,  Wlb,  NLAYER * INNER * INNER / 4);
  cvt_f32_bf16<<<1024, 256, 0, stream>>>(Wih, Wihb, HID_SZ * INNER / 4);
  cvt_f32_bf16<<<512,  256, 0, stream>>>(Wio, Wiob, OUT_SZ * INNER / 4);
  // 2. combined = concat(x, h) -> bf16
  build_combined<<<2048, 256, 0, stream>>>(x, h, act0);

  // 3. four square layers with ReLU, ping-pong act buffers
  dim3 blk(256);
  dim3 grid_sq(BATCH / 128, INNER / 128);
  unsigned short* a_in = act0;
  unsigned short* a_out = act1;
  for (int l = 0; l < NLAYER; ++l) {
    gemm_bt<0><<<grid_sq, blk, 0, stream>>>(a_in, Wlb + (long)l * INNER * INNER,
                                            bl + (long)l * INNER, a_out, INNER, INNER);
    unsigned short* t = a_in; a_in = a_out; a_out = t;
  }
  // a_in now holds the final combined activation

  // 4. hidden = tanh(combined @ W_i2h^T + b)
  dim3 grid_h(BATCH / 128, HID_SZ / 128);
  gemm_bt<1><<<grid_h, blk, 0, stream>>>(a_in, Wihb, bih, out_hidden, HID_SZ, INNER);
  // 5. output = combined @ W_i2o^T + b
  dim3 grid_o(BATCH / 128, OUT_SZ / 128);
  gemm_bt<2><<<grid_o, blk, 0, stream>>>(a_in, Wiob, bio, out_output, OUT_SZ, INNER);
}

// Round 2
// 441.175 us; speedup vs baseline: 1.1097x; 1.1097x over previous
//
#include <hip/hip_runtime.h>
#include <hip/hip_bf16.h>

// Problem constants
#define BATCH 4096
#define IN_SZ 512
#define HID_SZ 2048
#define OUT_SZ 512
#define NLAYER 4
#define INNER 2560        // 512 + 2048
#define NKT (INNER / 64)  // 40 K-tiles of 64

typedef __attribute__((ext_vector_type(8))) short bf16x8;
typedef __attribute__((ext_vector_type(4))) float f32x4;

__device__ __forceinline__ unsigned short f2bf(float f) {
  unsigned int u = __float_as_uint(f);
  u += 0x7fff + ((u >> 16) & 1);  // RNE
  return (unsigned short)(u >> 16);
}

__device__ __forceinline__ void gload16(const void* g, void* l) {
  __builtin_amdgcn_global_load_lds(
      (const __attribute__((address_space(1))) unsigned int*)g,
      (__attribute__((address_space(3))) unsigned int*)l,
      16, 0, 0);
}

// ---------------- conversion kernels ----------------

__global__ void cvt_f32_bf16(const float* __restrict__ in,
                             unsigned short* __restrict__ out, int n4) {
  int i = blockIdx.x * blockDim.x + threadIdx.x;
  const int stride = gridDim.x * blockDim.x;
  for (; i < n4; i += stride) {
    float4 v = *reinterpret_cast<const float4*>(in + (long)i * 4);
    ushort4 o;
    o.x = f2bf(v.x); o.y = f2bf(v.y); o.z = f2bf(v.z); o.w = f2bf(v.w);
    *reinterpret_cast<ushort4*>(out + (long)i * 4) = o;
  }
}

__global__ void build_combined(const float* __restrict__ x,
                               const float* __restrict__ h,
                               unsigned short* __restrict__ out) {
  const int n4 = BATCH * INNER / 4;
  int i = blockIdx.x * blockDim.x + threadIdx.x;
  const int stride = gridDim.x * blockDim.x;
  for (; i < n4; i += stride) {
    int row = i / (INNER / 4);
    int c4 = i - row * (INNER / 4);
    const float* src = (c4 < IN_SZ / 4) ? (x + (long)row * IN_SZ + c4 * 4)
                                        : (h + (long)row * HID_SZ + (c4 - IN_SZ / 4) * 4);
    float4 v = *reinterpret_cast<const float4*>(src);
    ushort4 o;
    o.x = f2bf(v.x); o.y = f2bf(v.y); o.z = f2bf(v.z); o.w = f2bf(v.w);
    *reinterpret_cast<ushort4*>(out + (long)i * 4) = o;
  }
}

// ---------------- 256x256 8-phase GEMM: C = act(A * B^T + bias) ----------------
// A: [4096][2560] bf16, B: [N=2560][2560] bf16 ('bi,oi->bo').
// 512 threads = 8 waves (2 M x 4 N), per-wave 128x64 output, BK=64.
// LDS: 2 bufs x (A 32KB + B 32KB) = 128 KB, XOR-swizzle byte^=((row&7)<<4).
// Counted vmcnt(6): 3 half-tiles (2 loads/thread each) in flight across barriers.
// MODE 0: relu -> bf16 C [4096][2560]
// MODE 1: fused heads: col<512 -> f32 output [4096][512]; col>=512 -> tanh f32 hidden [4096][2048]

// stage macros: one 16KB half-tile = 2 gload16/thread; LDS dest linear, source pre-swizzled
#define STAGE_A(kt, h, buf) do {                                                   \
  _Pragma("unroll")                                                                \
  for (int i_ = 0; i_ < 2; ++i_) {                                                 \
    int p_ = w + i_ * 8;                                                           \
    int grow_ = (p_ < 8) ? ((h) * 64 + p_ * 8) : (128 + (h) * 64 + (p_ - 8) * 8);  \
    gload16(A + (long)(row0 + grow_ + srow) * INNER + (kt) * 64 + srcsw,           \
            (void*)(&lds[buf][0] + grow_ * 64));                                   \
  } } while (0)

#define STAGE_B(kt, nh, buf) do {                                                  \
  _Pragma("unroll")                                                                \
  for (int i_ = 0; i_ < 2; ++i_) {                                                 \
    int p_ = w + i_ * 8;                                                           \
    int grow_ = (p_ >> 2) * 64 + (nh) * 32 + (p_ & 3) * 8;                         \
    gload16(B + (long)(col0 + grow_ + srow) * INNER + (kt) * 64 + srcsw,           \
            (void*)(&lds[buf][16384] + grow_ * 64));                               \
  } } while (0)

// one phase: 12 ds_read_b128 + setprio-wrapped 16 MFMA + end barrier
#define PHASE(mh, nh, buf) do {                                                    \
  const unsigned short* Ar_ = &lds[buf][0];                                        \
  const unsigned short* Br_ = &lds[buf][16384];                                    \
  bf16x8 af_[4][2], bg_[2][2];                                                     \
  _Pragma("unroll")                                                                \
  for (int m_ = 0; m_ < 4; ++m_) {                                                 \
    int r_ = arow + (mh) * 64 + m_ * 16;                                           \
    af_[m_][0] = *(const bf16x8*)(Ar_ + r_ * 64 + csw0);                           \
    af_[m_][1] = *(const bf16x8*)(Ar_ + r_ * 64 + csw1);                           \
  }                                                                                \
  _Pragma("unroll")                                                                \
  for (int n_ = 0; n_ < 2; ++n_) {                                                 \
    int r_ = brow + (nh) * 32 + n_ * 16;                                           \
    bg_[n_][0] = *(const bf16x8*)(Br_ + r_ * 64 + csw0);                           \
    bg_[n_][1] = *(const bf16x8*)(Br_ + r_ * 64 + csw1);                           \
  }                                                                                \
  __builtin_amdgcn_s_setprio(1);                                                   \
  _Pragma("unroll")                                                                \
  for (int m_ = 0; m_ < 4; ++m_)                                                   \
    _Pragma("unroll")                                                              \
    for (int n_ = 0; n_ < 2; ++n_) {                                               \
      acc[(mh) * 4 + m_][(nh) * 2 + n_] = __builtin_amdgcn_mfma_f32_16x16x32_bf16( \
          af_[m_][0], bg_[n_][0], acc[(mh) * 4 + m_][(nh) * 2 + n_], 0, 0, 0);     \
      acc[(mh) * 4 + m_][(nh) * 2 + n_] = __builtin_amdgcn_mfma_f32_16x16x32_bf16( \
          af_[m_][1], bg_[n_][1], acc[(mh) * 4 + m_][(nh) * 2 + n_], 0, 0, 0);     \
    }                                                                              \
  __builtin_amdgcn_s_setprio(0);                                                   \
  __builtin_amdgcn_s_barrier();                                                    \
} while (0)

template <int MODE>
__global__ __launch_bounds__(512, 2)
void gemm8(const unsigned short* __restrict__ A, const unsigned short* __restrict__ B,
           const float* __restrict__ bias0, const float* __restrict__ bias1,
           void* __restrict__ C) {
  __shared__ unsigned short lds[2][32768];  // 128 KiB

  const int tid = threadIdx.x;
  const int w = tid >> 6;
  const int lane = tid & 63;

  // XCD-chunked bijective swizzle: 160 blocks, 160 % 8 == 0
  const int flat = blockIdx.x;
  const int idx = (flat & 7) * 20 + (flat >> 3);
  const int mb = idx & 15;   // 16 M-blocks
  const int nb = idx >> 4;   // 10 N-blocks
  const int row0 = mb * 256, col0 = nb * 256;
  const int wr = w >> 2, wcn = w & 3;

  // stage source swizzle (elements): inverse of LDS read swizzle
  const int srow = lane >> 3;  // 0..7 row within 8-row piece
  const int srcsw = ((((lane & 7) << 4) ^ ((lane >> 3) << 4)) >> 1);

  // fragment read addressing
  const int fr = lane & 15;
  const int csw0 = ((((lane >> 4) << 4)) ^ ((lane & 7) << 4)) >> 1;        // kk=0
  const int csw1 = ((64 + ((lane >> 4) << 4)) ^ ((lane & 7) << 4)) >> 1;   // kk=1
  const int arow = wr * 128 + fr;
  const int brow = wcn * 64 + fr;

  f32x4 acc[8][4] = {};

  // prologue: tile 0 fully (4 half-tiles) + first 2 half-tiles of tile 1
  STAGE_A(0, 0, 0); STAGE_A(0, 1, 0); STAGE_B(0, 0, 0); STAGE_B(0, 1, 0);
  STAGE_A(1, 0, 1); STAGE_B(1, 0, 1);

  for (int T = 0; T < NKT; ++T) {
    const int d = T & 1;
    const int kt1 = (T + 1 < NKT) ? T + 1 : NKT - 1;  // clamped prefetch (garbage ok, never read)
    const int kt2 = (T + 2 < NKT) ? T + 2 : NKT - 1;

    // phase 0
    STAGE_A(kt1, 1, d ^ 1);
    asm volatile("s_waitcnt vmcnt(6)" ::: "memory");  // tile T fully landed, 3 half-tiles in flight
    __builtin_amdgcn_s_barrier();                     // all waves' vmcnt passed
    __builtin_amdgcn_sched_barrier(0);                // no ds_read hoist above the sync
    PHASE(0, 0, d);
    // phase 1
    STAGE_B(kt1, 1, d ^ 1);
    PHASE(0, 1, d);
    // phase 2 (A-half0 of buf d freed after phase 1's end barrier)
    STAGE_A(kt2, 0, d);
    PHASE(1, 0, d);
    // phase 3 (B-nh0 of buf d freed after phase 2's end barrier)
    STAGE_B(kt2, 0, d);
    PHASE(1, 1, d);
  }
  asm volatile("s_waitcnt vmcnt(0)" ::: "memory");

  // epilogue: C/D layout col = lane&15, row = (lane>>4)*4 + j
  const int erow = row0 + wr * 128 + ((lane >> 4) << 2);
  const int ecol = col0 + wcn * 64 + fr;
  if (MODE == 0) {
    unsigned short* Co = (unsigned short*)C;
#pragma unroll
    for (int n = 0; n < 4; ++n) {
      const int col = ecol + n * 16;
      const float bv = bias0[col];
#pragma unroll
      for (int m = 0; m < 8; ++m) {
        const int row = erow + m * 16;
#pragma unroll
        for (int j = 0; j < 4; ++j) {
          float v = acc[m][n][j] + bv;
          v = fmaxf(v, 0.0f);
          Co[(long)(row + j) * INNER + col] = f2bf(v);
        }
      }
    }
  } else {
    float* outO = (float*)C;                          // [4096,512]
    float* outH = (float*)C + (long)BATCH * OUT_SZ;   // [4096,2048]
#pragma unroll
    for (int n = 0; n < 4; ++n) {
      const int col = ecol + n * 16;
      if (col < OUT_SZ) {
        const float bv = bias0[col];
#pragma unroll
        for (int m = 0; m < 8; ++m) {
          const int row = erow + m * 16;
#pragma unroll
          for (int j = 0; j < 4; ++j)
            outO[(long)(row + j) * OUT_SZ + col] = acc[m][n][j] + bv;
        }
      } else {
        const int hc = col - OUT_SZ;
        const float bv = bias1[hc];
#pragma unroll
        for (int m = 0; m < 8; ++m) {
          const int row = erow + m * 16;
#pragma unroll
          for (int j = 0; j < 4; ++j)
            outH[(long)(row + j) * HID_SZ + hc] = tanhf(acc[m][n][j] + bv);
        }
      }
    }
  }
}

// ---------------- launcher ----------------

extern "C" void kernel_launch(void* const* d_in, const int* in_sizes, int n_in,
                              void* d_out, int out_size, void* d_ws, size_t ws_size,
                              hipStream_t stream) {
  const float* x   = (const float*)d_in[0];
  const float* h   = (const float*)d_in[1];
  const float* Wl  = (const float*)d_in[2];  // [4,2560,2560]
  const float* bl  = (const float*)d_in[3];  // [4,2560]
  const float* Wih = (const float*)d_in[4];  // [2048,2560]
  const float* bih = (const float*)d_in[5];  // [2048]
  const float* Wio = (const float*)d_in[6];  // [512,2560]
  const float* bio = (const float*)d_in[7];  // [512]

  unsigned short* ws   = (unsigned short*)d_ws;
  unsigned short* Wlb  = ws;                                   // 4*2560*2560
  unsigned short* Whb  = Wlb + (long)NLAYER * INNER * INNER;   // fused heads [2560][2560]: Wio rows 0-511, Wih rows 512-2559
  unsigned short* act0 = Whb + (long)INNER * INNER;
  unsigned short* act1 = act0 + (long)BATCH * INNER;

  // fp32 -> bf16 weight conversion
  cvt_f32_bf16<<<2048, 256, 0, stream>>>(Wl,  Wlb, NLAYER * INNER * INNER / 4);
  cvt_f32_bf16<<<256,  256, 0, stream>>>(Wio, Whb, OUT_SZ * INNER / 4);
  cvt_f32_bf16<<<1024, 256, 0, stream>>>(Wih, Whb + (long)OUT_SZ * INNER, HID_SZ * INNER / 4);
  build_combined<<<2048, 256, 0, stream>>>(x, h, act0);

  // 4 square layers, ping-pong
  unsigned short* a_in = act0;
  unsigned short* a_out = act1;
  for (int l = 0; l < NLAYER; ++l) {
    gemm8<0><<<160, 512, 0, stream>>>(a_in, Wlb + (long)l * INNER * INNER,
                                      bl + (long)l * INNER, nullptr, a_out);
    unsigned short* t = a_in; a_in = a_out; a_out = t;
  }

  // fused heads: output (cols 0-511) + tanh hidden (cols 512-2559)
  gemm8<1><<<160, 512, 0, stream>>>(a_in, Whb, bio, bih, d_out);
}

// Round 3
// 396.585 us; speedup vs baseline: 1.2344x; 1.1124x over previous
//
#include <hip/hip_runtime.h>
#include <hip/hip_bf16.h>

// Problem constants
#define BATCH 4096
#define IN_SZ 512
#define HID_SZ 2048
#define OUT_SZ 512
#define NLAYER 4
#define INNER 2560        // 512 + 2048
#define NKT (INNER / 64)  // 40 K-tiles of 64

typedef __attribute__((ext_vector_type(8))) short bf16x8;
typedef __attribute__((ext_vector_type(4))) float f32x4;

__device__ __forceinline__ unsigned short f2bf(float f) {
  unsigned int u = __float_as_uint(f);
  u += 0x7fff + ((u >> 16) & 1);  // RNE
  return (unsigned short)(u >> 16);
}

__device__ __forceinline__ void gload16(const void* g, void* l) {
  __builtin_amdgcn_global_load_lds(
      (const __attribute__((address_space(1))) unsigned int*)g,
      (__attribute__((address_space(3))) unsigned int*)l,
      16, 0, 0);
}

// ---------------- conversion kernels ----------------

__global__ void cvt_f32_bf16(const float* __restrict__ in,
                             unsigned short* __restrict__ out, int n4) {
  int i = blockIdx.x * blockDim.x + threadIdx.x;
  const int stride = gridDim.x * blockDim.x;
  for (; i < n4; i += stride) {
    float4 v = *reinterpret_cast<const float4*>(in + (long)i * 4);
    ushort4 o;
    o.x = f2bf(v.x); o.y = f2bf(v.y); o.z = f2bf(v.z); o.w = f2bf(v.w);
    *reinterpret_cast<ushort4*>(out + (long)i * 4) = o;
  }
}

__global__ void build_combined(const float* __restrict__ x,
                               const float* __restrict__ h,
                               unsigned short* __restrict__ out) {
  const int n4 = BATCH * INNER / 4;
  int i = blockIdx.x * blockDim.x + threadIdx.x;
  const int stride = gridDim.x * blockDim.x;
  for (; i < n4; i += stride) {
    int row = i / (INNER / 4);
    int c4 = i - row * (INNER / 4);
    const float* src = (c4 < IN_SZ / 4) ? (x + (long)row * IN_SZ + c4 * 4)
                                        : (h + (long)row * HID_SZ + (c4 - IN_SZ / 4) * 4);
    float4 v = *reinterpret_cast<const float4*>(src);
    ushort4 o;
    o.x = f2bf(v.x); o.y = f2bf(v.y); o.z = f2bf(v.z); o.w = f2bf(v.w);
    *reinterpret_cast<ushort4*>(out + (long)i * 4) = o;
  }
}

// ---------------- 256x256 8-phase GEMM: C = act(A * B^T + bias) ----------------
// A: [4096][2560] bf16, B: [N=2560][2560] bf16 ('bi,oi->bo').
// 512 threads = 8 waves (2 M x 4 N), per-wave 128x64 output, BK=64.
// LDS: 2 bufs x (A 32KB + B 32KB) = 128 KB, XOR-swizzle byte^=((row&7)<<4).
// m201 rhythm: per phase {ds_read issue; stage; [lgkm hint]; barrier; lgkmcnt(0);
// setprio(1) MFMA setprio(0); barrier}. vmcnt(4) at tile's last phase validates T+1.
// Quadrant order (0,0),(0,1),(1,1),(1,0): B regs (bq0/bq1) persist, reads 12/4/8/0.

#define STAGE_A(kt, h, buf) do {                                                   \
  _Pragma("unroll")                                                                \
  for (int i_ = 0; i_ < 2; ++i_) {                                                 \
    int p_ = w + i_ * 8;                                                           \
    int grow_ = (p_ < 8) ? ((h) * 64 + p_ * 8) : (128 + (h) * 64 + (p_ - 8) * 8);  \
    gload16(A + (long)(row0 + grow_ + srow) * INNER + (kt) * 64 + srcsw,           \
            (void*)(&lds[buf][0] + grow_ * 64));                                   \
  } } while (0)

#define STAGE_B(kt, nh, buf) do {                                                  \
  _Pragma("unroll")                                                                \
  for (int i_ = 0; i_ < 2; ++i_) {                                                 \
    int p_ = w + i_ * 8;                                                           \
    int grow_ = (p_ >> 2) * 64 + (nh) * 32 + (p_ & 3) * 8;                         \
    gload16(B + (long)(col0 + grow_ + srow) * INNER + (kt) * 64 + srcsw,           \
            (void*)(&lds[buf][16384] + grow_ * 64));                               \
  } } while (0)

#define LOAD_AF(mh, buf) do {                                                      \
  const unsigned short* Ar_ = &lds[buf][0];                                        \
  _Pragma("unroll")                                                                \
  for (int m_ = 0; m_ < 4; ++m_) {                                                 \
    int r_ = arow + (mh) * 64 + m_ * 16;                                           \
    af[m_][0] = *(const bf16x8*)(Ar_ + r_ * 64 + csw0);                            \
    af[m_][1] = *(const bf16x8*)(Ar_ + r_ * 64 + csw1);                            \
  } } while (0)

#define LOAD_BQ(bq, nh, buf) do {                                                  \
  const unsigned short* Br_ = &lds[buf][16384];                                    \
  _Pragma("unroll")                                                                \
  for (int n_ = 0; n_ < 2; ++n_) {                                                 \
    int r_ = brow + (nh) * 32 + n_ * 16;                                           \
    bq[n_][0] = *(const bf16x8*)(Br_ + r_ * 64 + csw0);                            \
    bq[n_][1] = *(const bf16x8*)(Br_ + r_ * 64 + csw1);                            \
  } } while (0)

#define MFMA_QUAD(mh, bq, nh) do {                                                 \
  __builtin_amdgcn_s_setprio(1);                                                   \
  _Pragma("unroll")                                                                \
  for (int m_ = 0; m_ < 4; ++m_)                                                   \
    _Pragma("unroll")                                                              \
    for (int n_ = 0; n_ < 2; ++n_) {                                               \
      acc[(mh) * 4 + m_][(nh) * 2 + n_] = __builtin_amdgcn_mfma_f32_16x16x32_bf16( \
          af[m_][0], bq[n_][0], acc[(mh) * 4 + m_][(nh) * 2 + n_], 0, 0, 0);       \
      acc[(mh) * 4 + m_][(nh) * 2 + n_] = __builtin_amdgcn_mfma_f32_16x16x32_bf16( \
          af[m_][1], bq[n_][1], acc[(mh) * 4 + m_][(nh) * 2 + n_], 0, 0, 0);       \
    }                                                                              \
  __builtin_amdgcn_s_setprio(0);                                                   \
} while (0)

#define SYNC_MFMA() do {                                                           \
  __builtin_amdgcn_s_barrier();                                                    \
  asm volatile("s_waitcnt lgkmcnt(0)" ::: "memory");                               \
  __builtin_amdgcn_sched_barrier(0);                                               \
} while (0)

template <int MODE>
__global__ __launch_bounds__(512, 2)
void gemm8(const unsigned short* __restrict__ A, const unsigned short* __restrict__ B,
           const float* __restrict__ bias0, const float* __restrict__ bias1,
           void* __restrict__ C) {
  __shared__ unsigned short lds[2][32768];  // 128 KiB

  const int tid = threadIdx.x;
  const int w = tid >> 6;
  const int lane = tid & 63;

  // XCD-chunked bijective swizzle: 160 blocks, 160 % 8 == 0
  const int flat = blockIdx.x;
  const int idx = (flat & 7) * 20 + (flat >> 3);
  const int mb = idx & 15;   // 16 M-blocks
  const int nb = idx >> 4;   // 10 N-blocks
  const int row0 = mb * 256, col0 = nb * 256;
  const int wr = w >> 2, wcn = w & 3;

  // stage source swizzle (elements): inverse of LDS read swizzle
  const int srow = lane >> 3;
  const int srcsw = ((((lane & 7) << 4) ^ ((lane >> 3) << 4)) >> 1);

  // fragment read addressing
  const int fr = lane & 15;
  const int csw0 = ((((lane >> 4) << 4)) ^ ((lane & 7) << 4)) >> 1;       // kk=0
  const int csw1 = ((64 + ((lane >> 4) << 4)) ^ ((lane & 7) << 4)) >> 1;  // kk=1
  const int arow = wr * 128 + fr;
  const int brow = wcn * 64 + fr;

  f32x4 acc[8][4] = {};
  bf16x8 af[4][2], bq0[2][2], bq1[2][2];

  // prologue: tile 0 fully + first halves of tile 1; validate tile 0
  STAGE_A(0, 0, 0); STAGE_A(0, 1, 0); STAGE_B(0, 0, 0); STAGE_B(0, 1, 0);
  STAGE_A(1, 0, 1); STAGE_B(1, 0, 1);
  asm volatile("s_waitcnt vmcnt(4)" ::: "memory");  // tile 0 landed; tile1-h0 in flight
  __builtin_amdgcn_s_barrier();
  __builtin_amdgcn_sched_barrier(0);

  for (int T = 0; T < NKT; ++T) {
    const int d = T & 1;
    const int kt1 = (T + 1 < NKT) ? T + 1 : NKT - 1;  // clamped (dup staging, never read)
    const int kt2 = (T + 2 < NKT) ? T + 2 : NKT - 1;

    // P0: quadrant (0,0) — 12 ds_reads
    LOAD_AF(0, d);
    LOAD_BQ(bq0, 0, d);
    STAGE_A(kt1, 1, d ^ 1);
    asm volatile("s_waitcnt lgkmcnt(8)" ::: "memory");
    SYNC_MFMA();
    MFMA_QUAD(0, bq0, 0);
    __builtin_amdgcn_s_barrier();

    // P1: quadrant (0,1) — 4 ds_reads (af persists)
    LOAD_BQ(bq1, 1, d);
    STAGE_B(kt1, 1, d ^ 1);
    SYNC_MFMA();
    MFMA_QUAD(0, bq1, 1);
    __builtin_amdgcn_s_barrier();

    // P2: quadrant (1,1) — 8 ds_reads (bq1 persists)
    LOAD_AF(1, d);
    STAGE_A(kt2, 0, d);
    SYNC_MFMA();
    MFMA_QUAD(1, bq1, 1);
    __builtin_amdgcn_s_barrier();

    // P3: quadrant (1,0) — 0 ds_reads (af, bq0 persist); validate tile T+1
    STAGE_B(kt2, 0, d);
    asm volatile("s_waitcnt vmcnt(4)" ::: "memory");  // tile T+1 fully landed
    __builtin_amdgcn_s_barrier();
    __builtin_amdgcn_sched_barrier(0);
    MFMA_QUAD(1, bq0, 0);
    __builtin_amdgcn_s_barrier();
  }
  asm volatile("s_waitcnt vmcnt(0)" ::: "memory");

  // epilogue: C/D layout col = lane&15, row = (lane>>4)*4 + j
  const int erow = row0 + wr * 128 + ((lane >> 4) << 2);
  const int ecol = col0 + wcn * 64 + fr;
  if (MODE == 0) {
    unsigned short* Co = (unsigned short*)C;
#pragma unroll
    for (int n = 0; n < 4; ++n) {
      const int col = ecol + n * 16;
      const float bv = bias0[col];
#pragma unroll
      for (int m = 0; m < 8; ++m) {
        const int row = erow + m * 16;
#pragma unroll
        for (int j = 0; j < 4; ++j) {
          float v = acc[m][n][j] + bv;
          v = fmaxf(v, 0.0f);
          Co[(long)(row + j) * INNER + col] = f2bf(v);
        }
      }
    }
  } else {
    float* outO = (float*)C;                          // [4096,512]
    float* outH = (float*)C + (long)BATCH * OUT_SZ;   // [4096,2048]
#pragma unroll
    for (int n = 0; n < 4; ++n) {
      const int col = ecol + n * 16;
      if (col < OUT_SZ) {
        const float bv = bias0[col];
#pragma unroll
        for (int m = 0; m < 8; ++m) {
          const int row = erow + m * 16;
#pragma unroll
          for (int j = 0; j < 4; ++j)
            outO[(long)(row + j) * OUT_SZ + col] = acc[m][n][j] + bv;
        }
      } else {
        const int hc = col - OUT_SZ;
        const float bv = bias1[hc];
#pragma unroll
        for (int m = 0; m < 8; ++m) {
          const int row = erow + m * 16;
#pragma unroll
          for (int j = 0; j < 4; ++j)
            outH[(long)(row + j) * HID_SZ + hc] = tanhf(acc[m][n][j] + bv);
        }
      }
    }
  }
}

// ---------------- launcher ----------------

extern "C" void kernel_launch(void* const* d_in, const int* in_sizes, int n_in,
                              void* d_out, int out_size, void* d_ws, size_t ws_size,
                              hipStream_t stream) {
  const float* x   = (const float*)d_in[0];
  const float* h   = (const float*)d_in[1];
  const float* Wl  = (const float*)d_in[2];  // [4,2560,2560]
  const float* bl  = (const float*)d_in[3];  // [4,2560]
  const float* Wih = (const float*)d_in[4];  // [2048,2560]
  const float* bih = (const float*)d_in[5];  // [2048]
  const float* Wio = (const float*)d_in[6];  // [512,2560]
  const float* bio = (const float*)d_in[7];  // [512]

  unsigned short* ws   = (unsigned short*)d_ws;
  unsigned short* Wlb  = ws;                                   // 4*2560*2560
  unsigned short* Whb  = Wlb + (long)NLAYER * INNER * INNER;   // fused heads [2560][2560]
  unsigned short* act0 = Whb + (long)INNER * INNER;
  unsigned short* act1 = act0 + (long)BATCH * INNER;

  // fp32 -> bf16 weight conversion
  cvt_f32_bf16<<<2048, 256, 0, stream>>>(Wl,  Wlb, NLAYER * INNER * INNER / 4);
  cvt_f32_bf16<<<256,  256, 0, stream>>>(Wio, Whb, OUT_SZ * INNER / 4);
  cvt_f32_bf16<<<1024, 256, 0, stream>>>(Wih, Whb + (long)OUT_SZ * INNER, HID_SZ * INNER / 4);
  build_combined<<<2048, 256, 0, stream>>>(x, h, act0);

  // 4 square layers, ping-pong
  unsigned short* a_in = act0;
  unsigned short* a_out = act1;
  for (int l = 0; l < NLAYER; ++l) {
    gemm8<0><<<160, 512, 0, stream>>>(a_in, Wlb + (long)l * INNER * INNER,
                                      bl + (long)l * INNER, nullptr, a_out);
    unsigned short* t = a_in; a_in = a_out; a_out = t;
  }

  // fused heads: output (cols 0-511) + tanh hidden (cols 512-2559)
  gemm8<1><<<160, 512, 0, stream>>>(a_in, Whb, bio, bih, d_out);
}

// Round 4
// 344.942 us; speedup vs baseline: 1.4193x; 1.1497x over previous
//
#include <hip/hip_runtime.h>
#include <hip/hip_bf16.h>

// Problem constants
#define BATCH 4096
#define IN_SZ 512
#define HID_SZ 2048
#define OUT_SZ 512
#define NLAYER 4
#define INNER 2560        // 512 + 2048
#define NKT (INNER / 64)  // 40 K-tiles of 64

// GEMM tile: BM=128 x BN=320, BK=64; grid 32x8 = 256 blocks = 1/CU (100% fill).
// 8 waves (2M x 4N): per-wave 64x80 = 4 m-frags x 5 n-frags.

typedef __attribute__((ext_vector_type(8))) short bf16x8;
typedef __attribute__((ext_vector_type(4))) float f32x4;

__device__ __forceinline__ unsigned short f2bf(float f) {
  unsigned int u = __float_as_uint(f);
  u += 0x7fff + ((u >> 16) & 1);  // RNE
  return (unsigned short)(u >> 16);
}

__device__ __forceinline__ void gload16(const void* g, void* l) {
  __builtin_amdgcn_global_load_lds(
      (const __attribute__((address_space(1))) unsigned int*)g,
      (__attribute__((address_space(3))) unsigned int*)l,
      16, 0, 0);
}

// ---------------- conversion kernels ----------------

__global__ void cvt_f32_bf16(const float* __restrict__ in,
                             unsigned short* __restrict__ out, int n4) {
  int i = blockIdx.x * blockDim.x + threadIdx.x;
  const int stride = gridDim.x * blockDim.x;
  for (; i < n4; i += stride) {
    float4 v = *reinterpret_cast<const float4*>(in + (long)i * 4);
    ushort4 o;
    o.x = f2bf(v.x); o.y = f2bf(v.y); o.z = f2bf(v.z); o.w = f2bf(v.w);
    *reinterpret_cast<ushort4*>(out + (long)i * 4) = o;
  }
}

__global__ void build_combined(const float* __restrict__ x,
                               const float* __restrict__ h,
                               unsigned short* __restrict__ out) {
  const int n4 = BATCH * INNER / 4;
  int i = blockIdx.x * blockDim.x + threadIdx.x;
  const int stride = gridDim.x * blockDim.x;
  for (; i < n4; i += stride) {
    int row = i / (INNER / 4);
    int c4 = i - row * (INNER / 4);
    const float* src = (c4 < IN_SZ / 4) ? (x + (long)row * IN_SZ + c4 * 4)
                                        : (h + (long)row * HID_SZ + (c4 - IN_SZ / 4) * 4);
    float4 v = *reinterpret_cast<const float4*>(src);
    ushort4 o;
    o.x = f2bf(v.x); o.y = f2bf(v.y); o.z = f2bf(v.z); o.w = f2bf(v.w);
    *reinterpret_cast<ushort4*>(out + (long)i * 4) = o;
  }
}

// ---------------- 128x320 8-phase GEMM: C = act(A * B^T + bias) ----------------
// A: [4096][2560] bf16, B: [2560][2560] bf16 ('bi,oi->bo').
// LDS: 2 bufs x (A 16KB + B 40KB) = 112 KB, XOR-swizzle byte^=((row&7)<<4).
// Staging: 7 units/K-tile (A:u0,u1 = 64 rows each; B:u2..u6 = 64 rows each),
// each unit = 1 gload16/thread. Rotation during tile T (reading buf d):
//   P0: (T+1)u5,u6 -> d^1   P1: (T+1)u0,u1 -> d^1
//   P2: (T+2)u2,u3 -> d     P3: (T+2)u4 -> d, vmcnt(3)
// Same-buffer B overwrite at P2+ is safe: all B reads of tile T done by P1's
// lgkmcnt(0)+barrier; A of buf d^1 last read at tile T-1's P2. vmcnt(3) at P3
// leaves exactly (T+2)'s 3 units in flight with T+1 fully landed.
// Quadrants: P0 MF(mh0,bqA n0-2), P1 MF(mh0,bqB n3-4), P2 MF(mh1,bqB), P3 MF(mh1,bqA).

#define STAGE_U(kt, u, buf) do {                                              \
  if ((u) < 2) {                                                              \
    const int base_ = (u) * 64 + w * 8;                                       \
    gload16(A + (long)(row0 + base_ + srow) * INNER + (kt) * 64 + srcsw,      \
            (void*)(&lds[buf][base_ * 64]));                                  \
  } else {                                                                    \
    const int base_ = ((u) - 2) * 64 + w * 8;                                 \
    gload16(B + (long)(col0 + base_ + srow) * INNER + (kt) * 64 + srcsw,      \
            (void*)(&lds[buf][8192 + base_ * 64]));                           \
  } } while (0)

#define LOAD_AF2(mh, buf) do {                                                \
  const unsigned short* Ar_ = &lds[buf][0];                                   \
  _Pragma("unroll")                                                           \
  for (int m_ = 0; m_ < 2; ++m_) {                                            \
    int r_ = wr * 64 + (mh) * 32 + m_ * 16 + fr;                              \
    af2[m_][0] = *(const bf16x8*)(Ar_ + r_ * 64 + csw0);                      \
    af2[m_][1] = *(const bf16x8*)(Ar_ + r_ * 64 + csw1);                      \
  } } while (0)

#define LOAD_BQA(buf) do {                                                    \
  const unsigned short* Br_ = &lds[buf][8192];                                \
  _Pragma("unroll")                                                           \
  for (int n_ = 0; n_ < 3; ++n_) {                                            \
    int r_ = wcn * 80 + n_ * 16 + fr;                                         \
    bqA[n_][0] = *(const bf16x8*)(Br_ + r_ * 64 + csw0);                      \
    bqA[n_][1] = *(const bf16x8*)(Br_ + r_ * 64 + csw1);                      \
  } } while (0)

#define LOAD_BQB(buf) do {                                                    \
  const unsigned short* Br_ = &lds[buf][8192];                                \
  _Pragma("unroll")                                                           \
  for (int n_ = 0; n_ < 2; ++n_) {                                            \
    int r_ = wcn * 80 + (3 + n_) * 16 + fr;                                   \
    bqB[n_][0] = *(const bf16x8*)(Br_ + r_ * 64 + csw0);                      \
    bqB[n_][1] = *(const bf16x8*)(Br_ + r_ * 64 + csw1);                      \
  } } while (0)

#define MF_A(mh) do {                                                         \
  __builtin_amdgcn_s_setprio(1);                                              \
  _Pragma("unroll")                                                           \
  for (int m_ = 0; m_ < 2; ++m_)                                              \
    _Pragma("unroll")                                                         \
    for (int n_ = 0; n_ < 3; ++n_) {                                          \
      acc[(mh) * 2 + m_][n_] = __builtin_amdgcn_mfma_f32_16x16x32_bf16(       \
          af2[m_][0], bqA[n_][0], acc[(mh) * 2 + m_][n_], 0, 0, 0);           \
      acc[(mh) * 2 + m_][n_] = __builtin_amdgcn_mfma_f32_16x16x32_bf16(       \
          af2[m_][1], bqA[n_][1], acc[(mh) * 2 + m_][n_], 0, 0, 0);           \
    }                                                                         \
  __builtin_amdgcn_s_setprio(0);                                              \
} while (0)

#define MF_B(mh) do {                                                         \
  __builtin_amdgcn_s_setprio(1);                                              \
  _Pragma("unroll")                                                           \
  for (int m_ = 0; m_ < 2; ++m_)                                              \
    _Pragma("unroll")                                                         \
    for (int n_ = 0; n_ < 2; ++n_) {                                          \
      acc[(mh) * 2 + m_][3 + n_] = __builtin_amdgcn_mfma_f32_16x16x32_bf16(   \
          af2[m_][0], bqB[n_][0], acc[(mh) * 2 + m_][3 + n_], 0, 0, 0);       \
      acc[(mh) * 2 + m_][3 + n_] = __builtin_amdgcn_mfma_f32_16x16x32_bf16(   \
          af2[m_][1], bqB[n_][1], acc[(mh) * 2 + m_][3 + n_], 0, 0, 0);       \
    }                                                                         \
  __builtin_amdgcn_s_setprio(0);                                              \
} while (0)

#define SYNC_MFMA() do {                                                      \
  __builtin_amdgcn_s_barrier();                                               \
  asm volatile("s_waitcnt lgkmcnt(0)" ::: "memory");                          \
  __builtin_amdgcn_sched_barrier(0);                                          \
} while (0)

template <int MODE>
__global__ __launch_bounds__(512, 2)
void gemm8(const unsigned short* __restrict__ A, const unsigned short* __restrict__ B,
           const float* __restrict__ bias0, const float* __restrict__ bias1,
           void* __restrict__ C) {
  __shared__ unsigned short lds[2][28672];  // 112 KiB: A [0,8192), B [8192,28672)

  const int tid = threadIdx.x;
  const int w = tid >> 6;
  const int lane = tid & 63;

  // XCD mapping: 256 blocks, nb = flat&7 -> each XCD owns one 320-col B panel
  const int flat = blockIdx.x;
  const int nb = flat & 7;    // 8 N-blocks
  const int mb = flat >> 3;   // 32 M-blocks
  const int row0 = mb * 128, col0 = nb * 320;
  const int wr = w >> 2, wcn = w & 3;

  // stage source swizzle (elements): inverse of LDS read swizzle
  const int srow = lane >> 3;
  const int srcsw = ((((lane & 7) << 4) ^ ((lane >> 3) << 4)) >> 1);

  // fragment read addressing
  const int fr = lane & 15;
  const int csw0 = ((((lane >> 4) << 4)) ^ ((lane & 7) << 4)) >> 1;       // kk=0
  const int csw1 = ((64 + ((lane >> 4) << 4)) ^ ((lane & 7) << 4)) >> 1;  // kk=1

  f32x4 acc[4][5] = {};
  bf16x8 af2[2][2], bqA[3][2], bqB[2][2];

  // prologue: tile 0 fully (7 units) + tile 1's u2,u3,u4
  STAGE_U(0, 0, 0); STAGE_U(0, 1, 0); STAGE_U(0, 2, 0); STAGE_U(0, 3, 0);
  STAGE_U(0, 4, 0); STAGE_U(0, 5, 0); STAGE_U(0, 6, 0);
  STAGE_U(1, 2, 1); STAGE_U(1, 3, 1); STAGE_U(1, 4, 1);
  asm volatile("s_waitcnt vmcnt(3)" ::: "memory");  // tile 0 landed
  __builtin_amdgcn_s_barrier();
  __builtin_amdgcn_sched_barrier(0);

  for (int T = 0; T < NKT; ++T) {
    const int d = T & 1;
    const int kt1 = (T + 1 < NKT) ? T + 1 : NKT - 1;  // clamped dup staging: race-safe, never read
    const int kt2 = (T + 2 < NKT) ? T + 2 : NKT - 1;

    // P0: 10 ds_reads, MFMA mh0 x bqA (12)
    LOAD_AF2(0, d);
    LOAD_BQA(d);
    STAGE_U(kt1, 5, d ^ 1); STAGE_U(kt1, 6, d ^ 1);
    asm volatile("s_waitcnt lgkmcnt(6)" ::: "memory");
    SYNC_MFMA();
    MF_A(0);
    __builtin_amdgcn_s_barrier();

    // P1: 4 ds_reads, MFMA mh0 x bqB (8)
    LOAD_BQB(d);
    STAGE_U(kt1, 0, d ^ 1); STAGE_U(kt1, 1, d ^ 1);
    SYNC_MFMA();
    MF_B(0);
    __builtin_amdgcn_s_barrier();

    // P2: 4 ds_reads, MFMA mh1 x bqB (8); B-of-buf-d overwrite safe (reads done at P1)
    LOAD_AF2(1, d);
    STAGE_U(kt2, 2, d); STAGE_U(kt2, 3, d);
    SYNC_MFMA();
    MF_B(1);
    __builtin_amdgcn_s_barrier();

    // P3: 0 ds_reads, MFMA mh1 x bqA (12); validate tile T+1
    STAGE_U(kt2, 4, d);
    asm volatile("s_waitcnt vmcnt(3)" ::: "memory");  // tile T+1 fully landed
    __builtin_amdgcn_s_barrier();
    __builtin_amdgcn_sched_barrier(0);
    MF_A(1);
    __builtin_amdgcn_s_barrier();
  }
  asm volatile("s_waitcnt vmcnt(0)" ::: "memory");

  // epilogue: C/D layout col = lane&15, row = (lane>>4)*4 + j
  const int erow = row0 + wr * 64 + ((lane >> 4) << 2);
  const int ecol = col0 + wcn * 80 + fr;
  if (MODE == 0) {
    unsigned short* Co = (unsigned short*)C;
#pragma unroll
    for (int n = 0; n < 5; ++n) {
      const int col = ecol + n * 16;
      const float bv = bias0[col];
#pragma unroll
      for (int m = 0; m < 4; ++m) {
        const int row = erow + m * 16;
#pragma unroll
        for (int j = 0; j < 4; ++j) {
          float v = acc[m][n][j] + bv;
          v = fmaxf(v, 0.0f);
          Co[(long)(row + j) * INNER + col] = f2bf(v);
        }
      }
    }
  } else {
    float* outO = (float*)C;                          // [4096,512]
    float* outH = (float*)C + (long)BATCH * OUT_SZ;   // [4096,2048]
#pragma unroll
    for (int n = 0; n < 5; ++n) {
      const int col = ecol + n * 16;
      if (col < OUT_SZ) {
        const float bv = bias0[col];
#pragma unroll
        for (int m = 0; m < 4; ++m) {
          const int row = erow + m * 16;
#pragma unroll
          for (int j = 0; j < 4; ++j)
            outO[(long)(row + j) * OUT_SZ + col] = acc[m][n][j] + bv;
        }
      } else {
        const int hc = col - OUT_SZ;
        const float bv = bias1[hc];
#pragma unroll
        for (int m = 0; m < 4; ++m) {
          const int row = erow + m * 16;
#pragma unroll
          for (int j = 0; j < 4; ++j)
            outH[(long)(row + j) * HID_SZ + hc] = tanhf(acc[m][n][j] + bv);
        }
      }
    }
  }
}

// ---------------- launcher ----------------

extern "C" void kernel_launch(void* const* d_in, const int* in_sizes, int n_in,
                              void* d_out, int out_size, void* d_ws, size_t ws_size,
                              hipStream_t stream) {
  const float* x   = (const float*)d_in[0];
  const float* h   = (const float*)d_in[1];
  const float* Wl  = (const float*)d_in[2];  // [4,2560,2560]
  const float* bl  = (const float*)d_in[3];  // [4,2560]
  const float* Wih = (const float*)d_in[4];  // [2048,2560]
  const float* bih = (const float*)d_in[5];  // [2048]
  const float* Wio = (const float*)d_in[6];  // [512,2560]
  const float* bio = (const float*)d_in[7];  // [512]

  unsigned short* ws   = (unsigned short*)d_ws;
  unsigned short* Wlb  = ws;                                   // 4*2560*2560
  unsigned short* Whb  = Wlb + (long)NLAYER * INNER * INNER;   // fused heads [2560][2560]
  unsigned short* act0 = Whb + (long)INNER * INNER;
  unsigned short* act1 = act0 + (long)BATCH * INNER;

  // fp32 -> bf16 weight conversion
  cvt_f32_bf16<<<2048, 256, 0, stream>>>(Wl,  Wlb, NLAYER * INNER * INNER / 4);
  cvt_f32_bf16<<<256,  256, 0, stream>>>(Wio, Whb, OUT_SZ * INNER / 4);
  cvt_f32_bf16<<<1024, 256, 0, stream>>>(Wih, Whb + (long)OUT_SZ * INNER, HID_SZ * INNER / 4);
  build_combined<<<2048, 256, 0, stream>>>(x, h, act0);

  // 4 square layers, ping-pong
  unsigned short* a_in = act0;
  unsigned short* a_out = act1;
  for (int l = 0; l < NLAYER; ++l) {
    gemm8<0><<<256, 512, 0, stream>>>(a_in, Wlb + (long)l * INNER * INNER,
                                      bl + (long)l * INNER, nullptr, a_out);
    unsigned short* t = a_in; a_in = a_out; a_out = t;
  }

  // fused heads: output (cols 0-511) + tanh hidden (cols 512-2559)
  gemm8<1><<<256, 512, 0, stream>>>(a_in, Whb, bio, bih, d_out);
}

// Round 5
// 310.673 us; speedup vs baseline: 1.5758x; 1.1103x over previous
//
#include <hip/hip_runtime.h>
#include <hip/hip_bf16.h>

// Problem constants
#define BATCH 4096
#define IN_SZ 512
#define HID_SZ 2048
#define OUT_SZ 512
#define NLAYER 4
#define INNER 2560        // 512 + 2048
#define NKT (INNER / 64)  // 40 K-tiles of 64 (even -> 2x-unrolled T loop is exact)

// GEMM tile: BM=128 x BN=320, BK=64; grid 32x8 = 256 blocks = 1/CU (100% fill).
// 8 waves (2M x 4N): per-wave 64x80 = 4 m-frags x 5 n-frags.
// NEW this round: fragment ds_reads pipelined one phase ahead with counted
// lgkmcnt so the LDS pipe drains DURING the MFMA clusters instead of before.

typedef __attribute__((ext_vector_type(8))) short bf16x8;
typedef __attribute__((ext_vector_type(4))) float f32x4;

__device__ __forceinline__ unsigned short f2bf(float f) {
  unsigned int u = __float_as_uint(f);
  u += 0x7fff + ((u >> 16) & 1);  // RNE
  return (unsigned short)(u >> 16);
}

__device__ __forceinline__ void gload16(const void* g, void* l) {
  __builtin_amdgcn_global_load_lds(
      (const __attribute__((address_space(1))) unsigned int*)g,
      (__attribute__((address_space(3))) unsigned int*)l,
      16, 0, 0);
}

// ---------------- conversion kernels ----------------

__global__ void cvt_f32_bf16(const float* __restrict__ in,
                             unsigned short* __restrict__ out, int n4) {
  int i = blockIdx.x * blockDim.x + threadIdx.x;
  const int stride = gridDim.x * blockDim.x;
  for (; i < n4; i += stride) {
    float4 v = *reinterpret_cast<const float4*>(in + (long)i * 4);
    ushort4 o;
    o.x = f2bf(v.x); o.y = f2bf(v.y); o.z = f2bf(v.z); o.w = f2bf(v.w);
    *reinterpret_cast<ushort4*>(out + (long)i * 4) = o;
  }
}

__global__ void build_combined(const float* __restrict__ x,
                               const float* __restrict__ h,
                               unsigned short* __restrict__ out) {
  const int n4 = BATCH * INNER / 4;
  int i = blockIdx.x * blockDim.x + threadIdx.x;
  const int stride = gridDim.x * blockDim.x;
  for (; i < n4; i += stride) {
    int row = i / (INNER / 4);
    int c4 = i - row * (INNER / 4);
    const float* src = (c4 < IN_SZ / 4) ? (x + (long)row * IN_SZ + c4 * 4)
                                        : (h + (long)row * HID_SZ + (c4 - IN_SZ / 4) * 4);
    float4 v = *reinterpret_cast<const float4*>(src);
    ushort4 o;
    o.x = f2bf(v.x); o.y = f2bf(v.y); o.z = f2bf(v.z); o.w = f2bf(v.w);
    *reinterpret_cast<ushort4*>(out + (long)i * 4) = o;
  }
}

// ---------------- 128x320 pipelined 4-phase GEMM: C = act(A * B^T + bias) ----
// A: [4096][2560] bf16, B: [2560][2560] bf16 ('bi,oi->bo').
// LDS: 2 bufs x (A 16KB + B 40KB) = 112 KB, XOR-swizzle byte^=((row&7)<<4).
// Staging: 7 units/K-tile (A:u0,u1; B:u2..u6; 64 rows each, 1 gload16/thread).
// Rotation during tile T (reading buf d):
//   P0: (T+1)u5,u6 -> d^1   P1: (T+1)u0,u1 -> d^1
//   P2: (T+2)u2,u3 -> d     P3: (T+2)u4 -> d; vmcnt(3) validates T+1
// Fragment-read pipeline (one phase ahead of use):
//   prev P3: afA,bqA of T (10 reads)  -> waited by lgkm(4) at P0-mid
//   P0: bqB of T (4)                  -> waited by lgkm(4) at P1-mid
//   P1: afB of T (4)                  -> waited by lgkm(0) at P2-mid
//   P3 (after vmcnt+barrier): afA',bqA' of T+1 into alternate reg set
// Quadrants: Q0=afA x bqA (12 MFMA), Q1=afA x bqB (8), Q2=afB x bqB (8),
//            Q3=afB x bqA (12). Reg sets ping-pong on tile parity (static idx).

#define STAGE_U(kt, u, buf) do {                                              \
  if ((u) < 2) {                                                              \
    const int base_ = (u) * 64 + w * 8;                                       \
    gload16(A + (long)(row0 + base_ + srow) * INNER + (kt) * 64 + srcsw,      \
            (void*)(&lds[buf][base_ * 64]));                                  \
  } else {                                                                    \
    const int base_ = ((u) - 2) * 64 + w * 8;                                 \
    gload16(B + (long)(col0 + base_ + srow) * INNER + (kt) * 64 + srcsw,      \
            (void*)(&lds[buf][8192 + base_ * 64]));                           \
  } } while (0)

#define LOAD_AF(dst, mh, buf) do {                                           \
  const unsigned short* Ar_ = &lds[buf][0];                                  \
  _Pragma("unroll")                                                          \
  for (int m_ = 0; m_ < 2; ++m_) {                                           \
    int r_ = wr * 64 + (mh) * 32 + m_ * 16 + fr;                             \
    dst[m_][0] = *(const bf16x8*)(Ar_ + r_ * 64 + csw0);                     \
    dst[m_][1] = *(const bf16x8*)(Ar_ + r_ * 64 + csw1);                     \
  } } while (0)

#define LOAD_BQA(dst, buf) do {                                              \
  const unsigned short* Br_ = &lds[buf][8192];                               \
  _Pragma("unroll")                                                          \
  for (int n_ = 0; n_ < 3; ++n_) {                                           \
    int r_ = wcn * 80 + n_ * 16 + fr;                                        \
    dst[n_][0] = *(const bf16x8*)(Br_ + r_ * 64 + csw0);                     \
    dst[n_][1] = *(const bf16x8*)(Br_ + r_ * 64 + csw1);                     \
  } } while (0)

#define LOAD_BQB(dst, buf) do {                                              \
  const unsigned short* Br_ = &lds[buf][8192];                               \
  _Pragma("unroll")                                                          \
  for (int n_ = 0; n_ < 2; ++n_) {                                           \
    int r_ = wcn * 80 + (3 + n_) * 16 + fr;                                  \
    dst[n_][0] = *(const bf16x8*)(Br_ + r_ * 64 + csw0);                     \
    dst[n_][1] = *(const bf16x8*)(Br_ + r_ * 64 + csw1);                     \
  } } while (0)

#define MF_A(af, bq, mh) do {                                                 \
  __builtin_amdgcn_s_setprio(1);                                              \
  _Pragma("unroll")                                                           \
  for (int m_ = 0; m_ < 2; ++m_)                                              \
    _Pragma("unroll")                                                         \
    for (int n_ = 0; n_ < 3; ++n_) {                                          \
      acc[(mh) * 2 + m_][n_] = __builtin_amdgcn_mfma_f32_16x16x32_bf16(       \
          af[m_][0], bq[n_][0], acc[(mh) * 2 + m_][n_], 0, 0, 0);             \
      acc[(mh) * 2 + m_][n_] = __builtin_amdgcn_mfma_f32_16x16x32_bf16(       \
          af[m_][1], bq[n_][1], acc[(mh) * 2 + m_][n_], 0, 0, 0);             \
    }                                                                         \
  __builtin_amdgcn_s_setprio(0);                                              \
} while (0)

#define MF_B(af, bq, mh) do {                                                 \
  __builtin_amdgcn_s_setprio(1);                                              \
  _Pragma("unroll")                                                           \
  for (int m_ = 0; m_ < 2; ++m_)                                              \
    _Pragma("unroll")                                                         \
    for (int n_ = 0; n_ < 2; ++n_) {                                          \
      acc[(mh) * 2 + m_][3 + n_] = __builtin_amdgcn_mfma_f32_16x16x32_bf16(   \
          af[m_][0], bq[n_][0], acc[(mh) * 2 + m_][3 + n_], 0, 0, 0);         \
      acc[(mh) * 2 + m_][3 + n_] = __builtin_amdgcn_mfma_f32_16x16x32_bf16(   \
          af[m_][1], bq[n_][1], acc[(mh) * 2 + m_][3 + n_], 0, 0, 0);         \
    }                                                                         \
  __builtin_amdgcn_s_setprio(0);                                              \
} while (0)

#define SB() __builtin_amdgcn_sched_barrier(0)

// Tile body. d = tile parity (compile-time), AC/QC = current afA/bqA sets,
// AN/QN = next-tile sets (loaded at P3).
#define TILE_BODY(d, AC, QC, AN, QN) do {                                     \
  const int T = T2 + (d);                                                     \
  const int kt1 = (T + 1 < NKT) ? T + 1 : NKT - 1;                            \
  const int kt2 = (T + 2 < NKT) ? T + 2 : NKT - 1;                            \
  /* P0: issue bqB(T); stage (T+1)u5,u6 -> d^1; MFMA Q0 = AC x QC */          \
  LOAD_BQB(bqB, d);                                                           \
  STAGE_U(kt1, 5, (d) ^ 1); STAGE_U(kt1, 6, (d) ^ 1);                         \
  SB();                                                                       \
  __builtin_amdgcn_s_barrier();                                               \
  asm volatile("s_waitcnt lgkmcnt(4)" ::: "memory");  /* AC,QC done */        \
  SB();                                                                       \
  MF_A(AC, QC, 0);                                                            \
  __builtin_amdgcn_s_barrier();                                               \
  /* P1: issue afB(T); stage (T+1)u0,u1 -> d^1; MFMA Q1 = AC x bqB */         \
  LOAD_AF(afB, 1, d);                                                         \
  STAGE_U(kt1, 0, (d) ^ 1); STAGE_U(kt1, 1, (d) ^ 1);                         \
  SB();                                                                       \
  __builtin_amdgcn_s_barrier();                                               \
  asm volatile("s_waitcnt lgkmcnt(4)" ::: "memory");  /* bqB done */          \
  SB();                                                                       \
  MF_B(AC, bqB, 0);                                                           \
  __builtin_amdgcn_s_barrier();                                               \
  /* P2: stage (T+2)u2,u3 -> d; MFMA Q2 = afB x bqB */                        \
  STAGE_U(kt2, 2, d); STAGE_U(kt2, 3, d);                                     \
  SB();                                                                       \
  __builtin_amdgcn_s_barrier();                                               \
  asm volatile("s_waitcnt lgkmcnt(0)" ::: "memory");  /* afB done */          \
  SB();                                                                       \
  MF_B(afB, bqB, 1);                                                          \
  __builtin_amdgcn_s_barrier();                                               \
  /* P3: stage (T+2)u4 -> d; validate T+1; issue next-tile afA,bqA; Q3 */     \
  STAGE_U(kt2, 4, d);                                                         \
  asm volatile("s_waitcnt vmcnt(3)" ::: "memory");  /* T+1 fully landed */    \
  __builtin_amdgcn_s_barrier();                                               \
  SB();                                                                       \
  LOAD_AF(AN, 0, (d) ^ 1);                                                    \
  LOAD_BQA(QN, (d) ^ 1);                                                      \
  SB();  /* pin read-issue before the MFMA cluster */                         \
  MF_A(afB, QC, 1);                                                           \
  __builtin_amdgcn_s_barrier();                                               \
} while (0)

template <int MODE>
__global__ __launch_bounds__(512, 2)
void gemm8(const unsigned short* __restrict__ A, const unsigned short* __restrict__ B,
           const float* __restrict__ bias0, const float* __restrict__ bias1,
           void* __restrict__ C) {
  __shared__ unsigned short lds[2][28672];  // 112 KiB: A [0,8192), B [8192,28672)

  const int tid = threadIdx.x;
  const int w = tid >> 6;
  const int lane = tid & 63;

  // XCD mapping: 256 blocks, nb = flat&7 -> each XCD owns one 320-col B panel
  const int flat = blockIdx.x;
  const int nb = flat & 7;    // 8 N-blocks
  const int mb = flat >> 3;   // 32 M-blocks
  const int row0 = mb * 128, col0 = nb * 320;
  const int wr = w >> 2, wcn = w & 3;

  // stage source swizzle (elements): inverse of LDS read swizzle
  const int srow = lane >> 3;
  const int srcsw = ((((lane & 7) << 4) ^ ((lane >> 3) << 4)) >> 1);

  // fragment read addressing
  const int fr = lane & 15;
  const int csw0 = ((((lane >> 4) << 4)) ^ ((lane & 7) << 4)) >> 1;       // kk=0
  const int csw1 = ((64 + ((lane >> 4) << 4)) ^ ((lane & 7) << 4)) >> 1;  // kk=1

  f32x4 acc[4][5] = {};
  bf16x8 afA0[2][2], afA1[2][2], afB[2][2];
  bf16x8 bqA0[3][2], bqA1[3][2], bqB[2][2];

  // prologue: tile 0 fully (7 units) + tile 1's u2,u3,u4; then first frag reads
  STAGE_U(0, 0, 0); STAGE_U(0, 1, 0); STAGE_U(0, 2, 0); STAGE_U(0, 3, 0);
  STAGE_U(0, 4, 0); STAGE_U(0, 5, 0); STAGE_U(0, 6, 0);
  STAGE_U(1, 2, 1); STAGE_U(1, 3, 1); STAGE_U(1, 4, 1);
  asm volatile("s_waitcnt vmcnt(3)" ::: "memory");  // tile 0 landed
  __builtin_amdgcn_s_barrier();
  SB();
  LOAD_AF(afA0, 0, 0);
  LOAD_BQA(bqA0, 0);
  SB();

  for (int T2 = 0; T2 < NKT; T2 += 2) {
    TILE_BODY(0, afA0, bqA0, afA1, bqA1);
    TILE_BODY(1, afA1, bqA1, afA0, bqA0);
  }
  asm volatile("s_waitcnt vmcnt(0)" ::: "memory");

  // epilogue: C/D layout col = lane&15, row = (lane>>4)*4 + j
  const int erow = row0 + wr * 64 + ((lane >> 4) << 2);
  const int ecol = col0 + wcn * 80 + fr;
  if (MODE == 0) {
    unsigned short* Co = (unsigned short*)C;
#pragma unroll
    for (int n = 0; n < 5; ++n) {
      const int col = ecol + n * 16;
      const float bv = bias0[col];
#pragma unroll
      for (int m = 0; m < 4; ++m) {
        const int row = erow + m * 16;
#pragma unroll
        for (int j = 0; j < 4; ++j) {
          float v = acc[m][n][j] + bv;
          v = fmaxf(v, 0.0f);
          Co[(long)(row + j) * INNER + col] = f2bf(v);
        }
      }
    }
  } else {
    float* outO = (float*)C;                          // [4096,512]
    float* outH = (float*)C + (long)BATCH * OUT_SZ;   // [4096,2048]
#pragma unroll
    for (int n = 0; n < 5; ++n) {
      const int col = ecol + n * 16;
      if (col < OUT_SZ) {
        const float bv = bias0[col];
#pragma unroll
        for (int m = 0; m < 4; ++m) {
          const int row = erow + m * 16;
#pragma unroll
          for (int j = 0; j < 4; ++j)
            outO[(long)(row + j) * OUT_SZ + col] = acc[m][n][j] + bv;
        }
      } else {
        const int hc = col - OUT_SZ;
        const float bv = bias1[hc];
#pragma unroll
        for (int m = 0; m < 4; ++m) {
          const int row = erow + m * 16;
#pragma unroll
          for (int j = 0; j < 4; ++j)
            outH[(long)(row + j) * HID_SZ + hc] = tanhf(acc[m][n][j] + bv);
        }
      }
    }
  }
}

// ---------------- launcher ----------------

extern "C" void kernel_launch(void* const* d_in, const int* in_sizes, int n_in,
                              void* d_out, int out_size, void* d_ws, size_t ws_size,
                              hipStream_t stream) {
  const float* x   = (const float*)d_in[0];
  const float* h   = (const float*)d_in[1];
  const float* Wl  = (const float*)d_in[2];  // [4,2560,2560]
  const float* bl  = (const float*)d_in[3];  // [4,2560]
  const float* Wih = (const float*)d_in[4];  // [2048,2560]
  const float* bih = (const float*)d_in[5];  // [2048]
  const float* Wio = (const float*)d_in[6];  // [512,2560]
  const float* bio = (const float*)d_in[7];  // [512]

  unsigned short* ws   = (unsigned short*)d_ws;
  unsigned short* Wlb  = ws;                                   // 4*2560*2560
  unsigned short* Whb  = Wlb + (long)NLAYER * INNER * INNER;   // fused heads [2560][2560]
  unsigned short* act0 = Whb + (long)INNER * INNER;
  unsigned short* act1 = act0 + (long)BATCH * INNER;

  // fp32 -> bf16 weight conversion
  cvt_f32_bf16<<<2048, 256, 0, stream>>>(Wl,  Wlb, NLAYER * INNER * INNER / 4);
  cvt_f32_bf16<<<256,  256, 0, stream>>>(Wio, Whb, OUT_SZ * INNER / 4);
  cvt_f32_bf16<<<1024, 256, 0, stream>>>(Wih, Whb + (long)OUT_SZ * INNER, HID_SZ * INNER / 4);
  build_combined<<<2048, 256, 0, stream>>>(x, h, act0);

  // 4 square layers, ping-pong
  unsigned short* a_in = act0;
  unsigned short* a_out = act1;
  for (int l = 0; l < NLAYER; ++l) {
    gemm8<0><<<256, 512, 0, stream>>>(a_in, Wlb + (long)l * INNER * INNER,
                                      bl + (long)l * INNER, nullptr, a_out);
    unsigned short* t = a_in; a_in = a_out; a_out = t;
  }

  // fused heads: output (cols 0-511) + tanh hidden (cols 512-2559)
  gemm8<1><<<256, 512, 0, stream>>>(a_in, Whb, bio, bih, d_out);
}

// Round 6
// 305.866 us; speedup vs baseline: 1.6006x; 1.0157x over previous
//
#include <hip/hip_runtime.h>
#include <hip/hip_bf16.h>

// Problem constants
#define BATCH 4096
#define IN_SZ 512
#define HID_SZ 2048
#define OUT_SZ 512
#define NLAYER 4
#define INNER 2560        // 512 + 2048
#define NKT (INNER / 64)  // 40 K-tiles of 64 (even -> 2x-unrolled T loop exact)

// GEMM tile: BM=128 x BN=160, BK=64; grid 32x16 = 512 blocks = 2/CU.
// 256 threads = 4 waves (2M x 2N): per-wave 64x80 = 4 m-frags x 5 n-frags.
// LDS 72 KB/block -> TWO blocks co-resident per CU: barrier/lgkm bubbles of one
// block are filled by the other block's MFMA (the round-5 structure was
// 1 block/CU and sync-bound at MfmaUtil 31%).

typedef __attribute__((ext_vector_type(8))) short bf16x8;
typedef __attribute__((ext_vector_type(4))) float f32x4;

__device__ __forceinline__ unsigned short f2bf(float f) {
  unsigned int u = __float_as_uint(f);
  u += 0x7fff + ((u >> 16) & 1);  // RNE
  return (unsigned short)(u >> 16);
}

__device__ __forceinline__ void gload16(const void* g, void* l) {
  __builtin_amdgcn_global_load_lds(
      (const __attribute__((address_space(1))) unsigned int*)g,
      (__attribute__((address_space(3))) unsigned int*)l,
      16, 0, 0);
}

// ---------------- conversion kernels ----------------

__global__ void cvt_f32_bf16(const float* __restrict__ in,
                             unsigned short* __restrict__ out, int n4) {
  int i = blockIdx.x * blockDim.x + threadIdx.x;
  const int stride = gridDim.x * blockDim.x;
  for (; i < n4; i += stride) {
    float4 v = *reinterpret_cast<const float4*>(in + (long)i * 4);
    ushort4 o;
    o.x = f2bf(v.x); o.y = f2bf(v.y); o.z = f2bf(v.z); o.w = f2bf(v.w);
    *reinterpret_cast<ushort4*>(out + (long)i * 4) = o;
  }
}

__global__ void build_combined(const float* __restrict__ x,
                               const float* __restrict__ h,
                               unsigned short* __restrict__ out) {
  const int n4 = BATCH * INNER / 4;
  int i = blockIdx.x * blockDim.x + threadIdx.x;
  const int stride = gridDim.x * blockDim.x;
  for (; i < n4; i += stride) {
    int row = i / (INNER / 4);
    int c4 = i - row * (INNER / 4);
    const float* src = (c4 < IN_SZ / 4) ? (x + (long)row * IN_SZ + c4 * 4)
                                        : (h + (long)row * HID_SZ + (c4 - IN_SZ / 4) * 4);
    float4 v = *reinterpret_cast<const float4*>(src);
    ushort4 o;
    o.x = f2bf(v.x); o.y = f2bf(v.y); o.z = f2bf(v.z); o.w = f2bf(v.w);
    *reinterpret_cast<ushort4*>(out + (long)i * 4) = o;
  }
}

// ---------------- 128x160 pipelined 4-phase GEMM: C = act(A * B^T + bias) ----
// A: [4096][2560] bf16, B: [2560][2560] bf16 ('bi,oi->bo').
// LDS: 2 bufs x (A 16KB + B 20KB) = 72 KB, XOR-swizzle byte^=((row&7)<<4).
// Staging: 9 units/K-tile (A: u0-3 = 32 rows each; B: u4-8 = 32 rows each),
// each unit = 1 gload16/thread (256 thr x 16B = 4KB = 32 rows of 128B).
// Rotation during tile T (reading buf d):
//   P0: (T+1)u6,u7,u8 -> d^1   P1: (T+1)u0,u1 -> d^1
//   P2: (T+2)u4,u5 -> d        P3: (T+2)u2,u3 -> d; vmcnt(4) validates T+1
// Fragment-read pipeline (one phase ahead of use):
//   prev P3: afA,bqA of T (10 reads) -> lgkm(4) at P0-mid
//   P0: bqB of T (4)                 -> lgkm(4) at P1-mid
//   P1: afB of T (4)                 -> lgkm(0) at P2-mid
//   P3 (after vmcnt+barrier): afA',bqA' of T+1 into alternate reg set
// Region-safety of every re-stage verified against read-completion barriers
// (B reads done by P1-end; A mh1 reads done by P2-end; bqA/afA by P0-end).

#define STAGE_U(kt, u, buf) do {                                              \
  if ((u) < 4) {                                                              \
    const int base_ = (u) * 32 + w * 8;                                       \
    gload16(A + (long)(row0 + base_ + srow) * INNER + (kt) * 64 + srcsw,      \
            (void*)(&lds[buf][base_ * 64]));                                  \
  } else {                                                                    \
    const int base_ = ((u) - 4) * 32 + w * 8;                                 \
    gload16(B + (long)(col0 + base_ + srow) * INNER + (kt) * 64 + srcsw,      \
            (void*)(&lds[buf][8192 + base_ * 64]));                           \
  } } while (0)

#define LOAD_AF(dst, mh, buf) do {                                           \
  const unsigned short* Ar_ = &lds[buf][0];                                  \
  _Pragma("unroll")                                                          \
  for (int m_ = 0; m_ < 2; ++m_) {                                           \
    int r_ = wr * 64 + (mh) * 32 + m_ * 16 + fr;                             \
    dst[m_][0] = *(const bf16x8*)(Ar_ + r_ * 64 + csw0);                     \
    dst[m_][1] = *(const bf16x8*)(Ar_ + r_ * 64 + csw1);                     \
  } } while (0)

#define LOAD_BQA(dst, buf) do {                                              \
  const unsigned short* Br_ = &lds[buf][8192];                               \
  _Pragma("unroll")                                                          \
  for (int n_ = 0; n_ < 3; ++n_) {                                           \
    int r_ = wcn * 80 + n_ * 16 + fr;                                        \
    dst[n_][0] = *(const bf16x8*)(Br_ + r_ * 64 + csw0);                     \
    dst[n_][1] = *(const bf16x8*)(Br_ + r_ * 64 + csw1);                     \
  } } while (0)

#define LOAD_BQB(dst, buf) do {                                              \
  const unsigned short* Br_ = &lds[buf][8192];                               \
  _Pragma("unroll")                                                          \
  for (int n_ = 0; n_ < 2; ++n_) {                                           \
    int r_ = wcn * 80 + (3 + n_) * 16 + fr;                                  \
    dst[n_][0] = *(const bf16x8*)(Br_ + r_ * 64 + csw0);                     \
    dst[n_][1] = *(const bf16x8*)(Br_ + r_ * 64 + csw1);                     \
  } } while (0)

#define MF_A(af, bq, mh) do {                                                 \
  __builtin_amdgcn_s_setprio(1);                                              \
  _Pragma("unroll")                                                           \
  for (int m_ = 0; m_ < 2; ++m_)                                              \
    _Pragma("unroll")                                                         \
    for (int n_ = 0; n_ < 3; ++n_) {                                          \
      acc[(mh) * 2 + m_][n_] = __builtin_amdgcn_mfma_f32_16x16x32_bf16(       \
          af[m_][0], bq[n_][0], acc[(mh) * 2 + m_][n_], 0, 0, 0);             \
      acc[(mh) * 2 + m_][n_] = __builtin_amdgcn_mfma_f32_16x16x32_bf16(       \
          af[m_][1], bq[n_][1], acc[(mh) * 2 + m_][n_], 0, 0, 0);             \
    }                                                                         \
  __builtin_amdgcn_s_setprio(0);                                              \
} while (0)

#define MF_B(af, bq, mh) do {                                                 \
  __builtin_amdgcn_s_setprio(1);                                              \
  _Pragma("unroll")                                                           \
  for (int m_ = 0; m_ < 2; ++m_)                                              \
    _Pragma("unroll")                                                         \
    for (int n_ = 0; n_ < 2; ++n_) {                                          \
      acc[(mh) * 2 + m_][3 + n_] = __builtin_amdgcn_mfma_f32_16x16x32_bf16(   \
          af[m_][0], bq[n_][0], acc[(mh) * 2 + m_][3 + n_], 0, 0, 0);         \
      acc[(mh) * 2 + m_][3 + n_] = __builtin_amdgcn_mfma_f32_16x16x32_bf16(   \
          af[m_][1], bq[n_][1], acc[(mh) * 2 + m_][3 + n_], 0, 0, 0);         \
    }                                                                         \
  __builtin_amdgcn_s_setprio(0);                                              \
} while (0)

#define SB() __builtin_amdgcn_sched_barrier(0)

// Tile body. d = tile parity (compile-time), AC/QC = current afA/bqA sets,
// AN/QN = next-tile sets (loaded at P3).
#define TILE_BODY(d, AC, QC, AN, QN) do {                                     \
  const int T = T2 + (d);                                                     \
  const int kt1 = (T + 1 < NKT) ? T + 1 : NKT - 1;                            \
  const int kt2 = (T + 2 < NKT) ? T + 2 : NKT - 1;                            \
  /* P0: issue bqB(T); stage (T+1)u6,u7,u8 -> d^1; MFMA Q0 = AC x QC */       \
  LOAD_BQB(bqB, d);                                                           \
  STAGE_U(kt1, 6, (d) ^ 1); STAGE_U(kt1, 7, (d) ^ 1); STAGE_U(kt1, 8, (d) ^ 1); \
  SB();                                                                       \
  __builtin_amdgcn_s_barrier();                                               \
  asm volatile("s_waitcnt lgkmcnt(4)" ::: "memory");  /* AC,QC done */        \
  SB();                                                                       \
  MF_A(AC, QC, 0);                                                            \
  __builtin_amdgcn_s_barrier();                                               \
  /* P1: issue afB(T); stage (T+1)u0,u1 -> d^1; MFMA Q1 = AC x bqB */         \
  LOAD_AF(afB, 1, d);                                                         \
  STAGE_U(kt1, 0, (d) ^ 1); STAGE_U(kt1, 1, (d) ^ 1);                         \
  SB();                                                                       \
  __builtin_amdgcn_s_barrier();                                               \
  asm volatile("s_waitcnt lgkmcnt(4)" ::: "memory");  /* bqB done */          \
  SB();                                                                       \
  MF_B(AC, bqB, 0);                                                           \
  __builtin_amdgcn_s_barrier();                                               \
  /* P2: stage (T+2)u4,u5 -> d; MFMA Q2 = afB x bqB */                        \
  STAGE_U(kt2, 4, d); STAGE_U(kt2, 5, d);                                     \
  SB();                                                                       \
  __builtin_amdgcn_s_barrier();                                               \
  asm volatile("s_waitcnt lgkmcnt(0)" ::: "memory");  /* afB done */          \
  SB();                                                                       \
  MF_B(afB, bqB, 1);                                                          \
  __builtin_amdgcn_s_barrier();                                               \
  /* P3: stage (T+2)u2,u3 -> d; validate T+1; issue next-tile afA,bqA; Q3 */  \
  STAGE_U(kt2, 2, d); STAGE_U(kt2, 3, d);                                     \
  asm volatile("s_waitcnt vmcnt(4)" ::: "memory");  /* T+1 fully landed */    \
  __builtin_amdgcn_s_barrier();                                               \
  SB();                                                                       \
  LOAD_AF(AN, 0, (d) ^ 1);                                                    \
  LOAD_BQA(QN, (d) ^ 1);                                                      \
  SB();  /* pin read-issue before the MFMA cluster */                         \
  MF_A(afB, QC, 1);                                                           \
  __builtin_amdgcn_s_barrier();                                               \
} while (0)

template <int MODE>
__global__ __launch_bounds__(256, 2)
void gemm8(const unsigned short* __restrict__ A, const unsigned short* __restrict__ B,
           const float* __restrict__ bias0, const float* __restrict__ bias1,
           void* __restrict__ C) {
  __shared__ unsigned short lds[2][18432];  // 72 KiB: A [0,8192), B [8192,18432)

  const int tid = threadIdx.x;
  const int w = tid >> 6;   // 4 waves
  const int lane = tid & 63;

  // XCD mapping: 512 blocks; each XCD owns 2 adjacent 160-col B panels
  const int flat = blockIdx.x;
  const int xcd = flat & 7;
  const int local = flat >> 3;           // 0..63
  const int nb = xcd * 2 + (local & 1);  // 16 N-blocks
  const int mb = local >> 1;             // 32 M-blocks
  const int row0 = mb * 128, col0 = nb * 160;
  const int wr = w >> 1, wcn = w & 1;

  // stage source swizzle (elements): inverse of LDS read swizzle
  const int srow = lane >> 3;
  const int srcsw = ((((lane & 7) << 4) ^ ((lane >> 3) << 4)) >> 1);

  // fragment read addressing
  const int fr = lane & 15;
  const int csw0 = ((((lane >> 4) << 4)) ^ ((lane & 7) << 4)) >> 1;       // kk=0
  const int csw1 = ((64 + ((lane >> 4) << 4)) ^ ((lane & 7) << 4)) >> 1;  // kk=1

  f32x4 acc[4][5] = {};
  bf16x8 afA0[2][2], afA1[2][2], afB[2][2];
  bf16x8 bqA0[3][2], bqA1[3][2], bqB[2][2];

  // prologue: tile 0 fully (9 units) + tile 1's u4,u5,u2,u3; then first frag reads
  STAGE_U(0, 0, 0); STAGE_U(0, 1, 0); STAGE_U(0, 2, 0); STAGE_U(0, 3, 0);
  STAGE_U(0, 4, 0); STAGE_U(0, 5, 0); STAGE_U(0, 6, 0); STAGE_U(0, 7, 0);
  STAGE_U(0, 8, 0);
  STAGE_U(1, 4, 1); STAGE_U(1, 5, 1); STAGE_U(1, 2, 1); STAGE_U(1, 3, 1);
  asm volatile("s_waitcnt vmcnt(4)" ::: "memory");  // tile 0 landed
  __builtin_amdgcn_s_barrier();
  SB();
  LOAD_AF(afA0, 0, 0);
  LOAD_BQA(bqA0, 0);
  SB();

  for (int T2 = 0; T2 < NKT; T2 += 2) {
    TILE_BODY(0, afA0, bqA0, afA1, bqA1);
    TILE_BODY(1, afA1, bqA1, afA0, bqA0);
  }
  asm volatile("s_waitcnt vmcnt(0)" ::: "memory");

  // epilogue: C/D layout col = lane&15, row = (lane>>4)*4 + j
  const int erow = row0 + wr * 64 + ((lane >> 4) << 2);
  const int ecol = col0 + wcn * 80 + fr;
  if (MODE == 0) {
    unsigned short* Co = (unsigned short*)C;
#pragma unroll
    for (int n = 0; n < 5; ++n) {
      const int col = ecol + n * 16;
      const float bv = bias0[col];
#pragma unroll
      for (int m = 0; m < 4; ++m) {
        const int row = erow + m * 16;
#pragma unroll
        for (int j = 0; j < 4; ++j) {
          float v = acc[m][n][j] + bv;
          v = fmaxf(v, 0.0f);
          Co[(long)(row + j) * INNER + col] = f2bf(v);
        }
      }
    }
  } else {
    float* outO = (float*)C;                          // [4096,512]
    float* outH = (float*)C + (long)BATCH * OUT_SZ;   // [4096,2048]
#pragma unroll
    for (int n = 0; n < 5; ++n) {
      const int col = ecol + n * 16;
      if (col < OUT_SZ) {
        const float bv = bias0[col];
#pragma unroll
        for (int m = 0; m < 4; ++m) {
          const int row = erow + m * 16;
#pragma unroll
          for (int j = 0; j < 4; ++j)
            outO[(long)(row + j) * OUT_SZ + col] = acc[m][n][j] + bv;
        }
      } else {
        const int hc = col - OUT_SZ;
        const float bv = bias1[hc];
#pragma unroll
        for (int m = 0; m < 4; ++m) {
          const int row = erow + m * 16;
#pragma unroll
          for (int j = 0; j < 4; ++j)
            outH[(long)(row + j) * HID_SZ + hc] = tanhf(acc[m][n][j] + bv);
        }
      }
    }
  }
}

// ---------------- launcher ----------------

extern "C" void kernel_launch(void* const* d_in, const int* in_sizes, int n_in,
                              void* d_out, int out_size, void* d_ws, size_t ws_size,
                              hipStream_t stream) {
  const float* x   = (const float*)d_in[0];
  const float* h   = (const float*)d_in[1];
  const float* Wl  = (const float*)d_in[2];  // [4,2560,2560]
  const float* bl  = (const float*)d_in[3];  // [4,2560]
  const float* Wih = (const float*)d_in[4];  // [2048,2560]
  const float* bih = (const float*)d_in[5];  // [2048]
  const float* Wio = (const float*)d_in[6];  // [512,2560]
  const float* bio = (const float*)d_in[7];  // [512]

  unsigned short* ws   = (unsigned short*)d_ws;
  unsigned short* Wlb  = ws;                                   // 4*2560*2560
  unsigned short* Whb  = Wlb + (long)NLAYER * INNER * INNER;   // fused heads [2560][2560]
  unsigned short* act0 = Whb + (long)INNER * INNER;
  unsigned short* act1 = act0 + (long)BATCH * INNER;

  // fp32 -> bf16 weight conversion
  cvt_f32_bf16<<<2048, 256, 0, stream>>>(Wl,  Wlb, NLAYER * INNER * INNER / 4);
  cvt_f32_bf16<<<256,  256, 0, stream>>>(Wio, Whb, OUT_SZ * INNER / 4);
  cvt_f32_bf16<<<1024, 256, 0, stream>>>(Wih, Whb + (long)OUT_SZ * INNER, HID_SZ * INNER / 4);
  build_combined<<<2048, 256, 0, stream>>>(x, h, act0);

  // 4 square layers, ping-pong
  unsigned short* a_in = act0;
  unsigned short* a_out = act1;
  for (int l = 0; l < NLAYER; ++l) {
    gemm8<0><<<512, 256, 0, stream>>>(a_in, Wlb + (long)l * INNER * INNER,
                                      bl + (long)l * INNER, nullptr, a_out);
    unsigned short* t = a_in; a_in = a_out; a_out = t;
  }

  // fused heads: output (cols 0-511) + tanh hidden (cols 512-2559)
  gemm8<1><<<512, 256, 0, stream>>>(a_in, Whb, bio, bih, d_out);
}